// Round 1
// baseline (6007.600 us; speedup 1.0000x reference)
//
#include <hip/hip_runtime.h>

#define CIN  32
#define COUT 32
#define KK   27
#define TPB  128   // conv block size: 2 waves, 128 nodes/block

// ---------------- Kernel 1: transpose x [Cin,N] -> xT [N,Cin] ----------------
__global__ __launch_bounds__(256) void transpose_k(const float* __restrict__ in,
                                                   float* __restrict__ xT, int N) {
    __shared__ float tile[32][33];
    int n0 = blockIdx.x * 32;
    int tx = threadIdx.x & 31;
    int ty = threadIdx.x >> 5;  // 0..7
#pragma unroll
    for (int c = ty; c < 32; c += 8) {
        int n = n0 + tx;
        tile[c][tx] = (n < N) ? in[(long)c * N + n] : 0.f;
    }
    __syncthreads();
#pragma unroll
    for (int nn = ty; nn < 32; nn += 8) {
        int n = n0 + nn;
        if (n < N) xT[(long)n * 32 + tx] = tile[tx][nn];
    }
}

// ---------------- Kernel 2: conv + per-wave BN partials ----------------
// thread = node. acc[32] in VGPRs. weight slice (4KB) double-buffered in LDS,
// read as wave-uniform (broadcast) ds_read_b128. Gather pipelined 1 tap ahead.
__global__ __launch_bounds__(TPB, 2) void conv_k(const float* __restrict__ xT,
                                                 const int* __restrict__ neigh,
                                                 const float* __restrict__ weight,
                                                 float* __restrict__ y,        // d_out, [COUT][N]
                                                 float* __restrict__ partial,  // [nrows][64]
                                                 int N) {
    __shared__ __align__(16) float lw[2][CIN * COUT];

    const int tid   = threadIdx.x;
    const int n     = blockIdx.x * TPB + tid;
    const bool valid = (n < N);
    const long nb   = (long)(valid ? n : (N - 1)) * KK;

    // stage w[0] into lw[0]: 1024 floats / 128 threads = 2 float4 each
    {
        const float4* wsrc = (const float4*)weight;
        float4 a = wsrc[tid * 2];
        float4 b = wsrc[tid * 2 + 1];
        ((float4*)lw[0])[tid * 2]     = a;
        ((float4*)lw[0])[tid * 2 + 1] = b;
    }

    float acc[32];
#pragma unroll
    for (int d = 0; d < 32; ++d) acc[d] = 0.f;

    // prefetch gather for tap 0
    int m0 = neigh[nb];
    float4 xv[8];
    {
        const float4* xr = (const float4*)(xT + (long)m0 * CIN);
#pragma unroll
        for (int i = 0; i < 8; ++i) xv[i] = xr[i];
    }
    int m_nxt = neigh[nb + 1];

    __syncthreads();

    for (int k = 0; k < KK; ++k) {
        const int p = k & 1;
        float4 wpre0, wpre1;
        float4 xn[8];
        if (k < KK - 1) {
            // prefetch next weight slice into regs
            const float4* ws2 = (const float4*)(weight + (k + 1) * (CIN * COUT));
            wpre0 = ws2[tid * 2];
            wpre1 = ws2[tid * 2 + 1];
            // prefetch next gather
            const float4* xr2 = (const float4*)(xT + (long)m_nxt * CIN);
#pragma unroll
            for (int i = 0; i < 8; ++i) xn[i] = xr2[i];
            int kidx = (k + 2 < KK) ? (k + 2) : (KK - 1);
            m_nxt = neigh[nb + kidx];
        }

        // compute tap k from lw[p] (wave-uniform broadcast reads)
        const float4* wl = (const float4*)lw[p];
        auto dotc = [&](float xs, const float4* wrow) {
#pragma unroll
            for (int d4 = 0; d4 < 8; ++d4) {
                float4 wq = wrow[d4];
                acc[d4 * 4 + 0] = fmaf(xs, wq.x, acc[d4 * 4 + 0]);
                acc[d4 * 4 + 1] = fmaf(xs, wq.y, acc[d4 * 4 + 1]);
                acc[d4 * 4 + 2] = fmaf(xs, wq.z, acc[d4 * 4 + 2]);
                acc[d4 * 4 + 3] = fmaf(xs, wq.w, acc[d4 * 4 + 3]);
            }
        };
#pragma unroll
        for (int c4 = 0; c4 < 8; ++c4) {
            float4 xq = xv[c4];
            dotc(xq.x, wl + ((c4 * 4 + 0) << 3));
            dotc(xq.y, wl + ((c4 * 4 + 1) << 3));
            dotc(xq.z, wl + ((c4 * 4 + 2) << 3));
            dotc(xq.w, wl + ((c4 * 4 + 3) << 3));
        }

        if (k < KK - 1) {
            // store prefetched slice to other buffer, rotate gather regs
            ((float4*)lw[p ^ 1])[tid * 2]     = wpre0;
            ((float4*)lw[p ^ 1])[tid * 2 + 1] = wpre1;
#pragma unroll
            for (int i = 0; i < 8; ++i) xv[i] = xn[i];
        }
        __syncthreads();
    }

    // write y in [d][N] layout (coalesced per d)
    if (valid) {
#pragma unroll
        for (int d = 0; d < 32; ++d) y[(long)d * N + n] = acc[d];
    } else {
#pragma unroll
        for (int d = 0; d < 32; ++d) acc[d] = 0.f;
    }

    // per-wave reduction of sum / sumsq via 64-lane butterfly
    const int lane = tid & 63;
    const int wrow = blockIdx.x * (TPB / 64) + (tid >> 6);
#pragma unroll
    for (int d = 0; d < 32; ++d) {
        float s = acc[d];
        float q = acc[d] * acc[d];
#pragma unroll
        for (int off = 1; off < 64; off <<= 1) {
            s += __shfl_xor(s, off, 64);
            q += __shfl_xor(q, off, 64);
        }
        if (lane == 0) {
            partial[(long)wrow * 64 + d]      = s;
            partial[(long)wrow * 64 + 32 + d] = q;
        }
    }
}

// ---------------- Kernel 3: reduce partials -> scale/shift ----------------
__global__ __launch_bounds__(256) void stats_k(const float* __restrict__ partial, int nrows,
                                               const float* __restrict__ gamma,
                                               const float* __restrict__ beta,
                                               float* __restrict__ ss, int N) {
    __shared__ float red[256];
    int tid = threadIdx.x;
    int col = tid & 63;
    int grp = tid >> 6;  // 0..3
    float s = 0.f;
    for (int r = grp; r < nrows; r += 4) s += partial[(long)r * 64 + col];
    red[tid] = s;
    __syncthreads();
    if (tid < 64) {
        red[tid] = red[tid] + red[tid + 64] + red[tid + 128] + red[tid + 192];
    }
    __syncthreads();
    if (tid < 32) {
        float mean = red[tid] / (float)N;
        float var  = red[tid + 32] / (float)N - mean * mean;
        float sc   = gamma[tid] * rsqrtf(var + 1e-3f);
        ss[tid]      = sc;
        ss[tid + 32] = beta[tid] - mean * sc;
    }
}

// ---------------- Kernel 4: in-place normalize of y ----------------
__global__ __launch_bounds__(256) void norm_k(float* __restrict__ y,
                                              const float* __restrict__ ss, int N) {
    int d = blockIdx.y;
    int i = blockIdx.x * blockDim.x + threadIdx.x;
    float sc = ss[d];
    float sh = ss[d + 32];
    int base = i * 4;
    if (base + 3 < N) {
        float4* p = (float4*)(y + (long)d * N + base);
        float4 v = *p;
        v.x = fmaf(v.x, sc, sh);
        v.y = fmaf(v.y, sc, sh);
        v.z = fmaf(v.z, sc, sh);
        v.w = fmaf(v.w, sc, sh);
        *p = v;
    } else if (base < N) {
        for (int t = base; t < N; ++t) y[(long)d * N + t] = fmaf(y[(long)d * N + t], sc, sh);
    }
}

// ---------------- launcher ----------------
extern "C" void kernel_launch(void* const* d_in, const int* in_sizes, int n_in,
                              void* d_out, int out_size, void* d_ws, size_t ws_size,
                              hipStream_t stream) {
    const float* data_in = (const float*)d_in[0];
    const int*   neigh   = (const int*)d_in[1];
    const float* weight  = (const float*)d_in[2];
    const float* gamma   = (const float*)d_in[3];
    const float* beta    = (const float*)d_in[4];
    float* out = (float*)d_out;

    const int N = in_sizes[1] / KK;

    float* xT = (float*)d_ws;                        // N*32 floats
    const int nblk  = (N + TPB - 1) / TPB;           // conv blocks
    const int nrows = nblk * (TPB / 64);             // waves (partial rows)
    float* partial = xT + (size_t)N * CIN;           // nrows*64 floats
    float* ss      = partial + (size_t)nrows * 64;   // 64 floats

    transpose_k<<<(N + 31) / 32, 256, 0, stream>>>(data_in, xT, N);
    conv_k<<<nblk, TPB, 0, stream>>>(xT, neigh, weight, out, partial, N);
    stats_k<<<1, 256, 0, stream>>>(partial, nrows, gamma, beta, ss, N);
    dim3 ngrid(((N + 3) / 4 + 255) / 256, COUT);
    norm_k<<<ngrid, 256, 0, stream>>>(out, ss, N);
}

// Round 2
// 340.646 us; speedup vs baseline: 17.6359x; 17.6359x over previous
//
#include <hip/hip_runtime.h>

#define CIN  32
#define COUT 32
#define KK   27
#define TPB  256   // conv block size: 4 waves

// ---------------- Kernel 1: transpose x [Cin,N] -> xT [N,Cin] ----------------
__global__ __launch_bounds__(256) void transpose_k(const float* __restrict__ in,
                                                   float* __restrict__ xT, int N) {
    __shared__ float tile[32][33];
    int n0 = blockIdx.x * 32;
    int tx = threadIdx.x & 31;
    int ty = threadIdx.x >> 5;  // 0..7
#pragma unroll
    for (int c = ty; c < 32; c += 8) {
        int n = n0 + tx;
        tile[c][tx] = (n < N) ? in[(long)c * N + n] : 0.f;
    }
    __syncthreads();
#pragma unroll
    for (int nn = ty; nn < 32; nn += 8) {
        int n = n0 + nn;
        if (n < N) xT[(long)n * 32 + tx] = tile[tx][nn];
    }
}

// ---------------- Kernel 2: conv + per-wave BN partials ----------------
// thread = node. acc[32] in VGPRs (no lambda, no address-taken arrays).
// Weights are wave-uniform -> compiler emits scalar s_load into SGPRs;
// no LDS, no barriers. Gather rows of xT are contiguous 128B -> dwordx4 loads.
__global__ __launch_bounds__(TPB, 4) void conv_k(const float* __restrict__ xT,
                                                 const int* __restrict__ neigh,
                                                 const float* __restrict__ weight,
                                                 float* __restrict__ y,        // d_out, [COUT][N]
                                                 float* __restrict__ partial,  // [nrows][64]
                                                 int N) {
    const int tid   = threadIdx.x;
    const int n     = blockIdx.x * TPB + tid;
    const bool valid = (n < N);
    const long nb   = (long)(valid ? n : 0) * KK;

    float acc[COUT];
#pragma unroll
    for (int d = 0; d < COUT; ++d) acc[d] = 0.f;

    int m = neigh[nb];

#pragma unroll 1
    for (int k = 0; k < KK; ++k) {
        // gather this tap's 32 features (contiguous 128 B)
        const float4* xr = (const float4*)(xT + (long)m * CIN);
        float4 xv0 = xr[0], xv1 = xr[1], xv2 = xr[2], xv3 = xr[3];
        float4 xv4 = xr[4], xv5 = xr[5], xv6 = xr[6], xv7 = xr[7];
        // prefetch next neighbor index (unconditional, clamped)
        m = neigh[nb + ((k + 1 < KK) ? (k + 1) : (KK - 1))];

        const float* wk = weight + k * (CIN * COUT);
#pragma unroll
        for (int c4 = 0; c4 < 8; ++c4) {
            float xs0, xs1, xs2, xs3;
            switch (c4) {
                case 0: xs0 = xv0.x; xs1 = xv0.y; xs2 = xv0.z; xs3 = xv0.w; break;
                case 1: xs0 = xv1.x; xs1 = xv1.y; xs2 = xv1.z; xs3 = xv1.w; break;
                case 2: xs0 = xv2.x; xs1 = xv2.y; xs2 = xv2.z; xs3 = xv2.w; break;
                case 3: xs0 = xv3.x; xs1 = xv3.y; xs2 = xv3.z; xs3 = xv3.w; break;
                case 4: xs0 = xv4.x; xs1 = xv4.y; xs2 = xv4.z; xs3 = xv4.w; break;
                case 5: xs0 = xv5.x; xs1 = xv5.y; xs2 = xv5.z; xs3 = xv5.w; break;
                case 6: xs0 = xv6.x; xs1 = xv6.y; xs2 = xv6.z; xs3 = xv6.w; break;
                default: xs0 = xv7.x; xs1 = xv7.y; xs2 = xv7.z; xs3 = xv7.w; break;
            }
            const float* w0 = wk + (c4 * 4 + 0) * COUT;
            const float* w1 = wk + (c4 * 4 + 1) * COUT;
            const float* w2 = wk + (c4 * 4 + 2) * COUT;
            const float* w3 = wk + (c4 * 4 + 3) * COUT;
#pragma unroll
            for (int d = 0; d < COUT; ++d) {
                acc[d] = fmaf(xs0, w0[d], acc[d]);
                acc[d] = fmaf(xs1, w1[d], acc[d]);
                acc[d] = fmaf(xs2, w2[d], acc[d]);
                acc[d] = fmaf(xs3, w3[d], acc[d]);
            }
        }
    }

    // write y in [d][N] layout (coalesced per d)
    if (valid) {
#pragma unroll
        for (int d = 0; d < COUT; ++d) y[(long)d * N + n] = acc[d];
    } else {
#pragma unroll
        for (int d = 0; d < COUT; ++d) acc[d] = 0.f;
    }

    // per-wave reduction of sum / sumsq via 64-lane butterfly
    const int lane = tid & 63;
    const int wrow = blockIdx.x * (TPB / 64) + (tid >> 6);
#pragma unroll
    for (int d = 0; d < COUT; ++d) {
        float s = acc[d];
        float q = acc[d] * acc[d];
#pragma unroll
        for (int off = 1; off < 64; off <<= 1) {
            s += __shfl_xor(s, off, 64);
            q += __shfl_xor(q, off, 64);
        }
        if (lane == 0) {
            partial[(long)wrow * 64 + d]      = s;
            partial[(long)wrow * 64 + 32 + d] = q;
        }
    }
}

// ---------------- Kernel 3: reduce partials -> scale/shift ----------------
__global__ __launch_bounds__(256) void stats_k(const float* __restrict__ partial, int nrows,
                                               const float* __restrict__ gamma,
                                               const float* __restrict__ beta,
                                               float* __restrict__ ss, int N) {
    __shared__ float red[256];
    int tid = threadIdx.x;
    int col = tid & 63;
    int grp = tid >> 6;  // 0..3
    float s = 0.f;
    for (int r = grp; r < nrows; r += 4) s += partial[(long)r * 64 + col];
    red[tid] = s;
    __syncthreads();
    if (tid < 64) {
        red[tid] = red[tid] + red[tid + 64] + red[tid + 128] + red[tid + 192];
    }
    __syncthreads();
    if (tid < 32) {
        float mean = red[tid] / (float)N;
        float var  = red[tid + 32] / (float)N - mean * mean;
        float sc   = gamma[tid] * rsqrtf(var + 1e-3f);
        ss[tid]      = sc;
        ss[tid + 32] = beta[tid] - mean * sc;
    }
}

// ---------------- Kernel 4: in-place normalize of y ----------------
__global__ __launch_bounds__(256) void norm_k(float* __restrict__ y,
                                              const float* __restrict__ ss, int N) {
    int d = blockIdx.y;
    int i = blockIdx.x * blockDim.x + threadIdx.x;
    float sc = ss[d];
    float sh = ss[d + 32];
    int base = i * 4;
    if (base + 3 < N) {
        float4* p = (float4*)(y + (long)d * N + base);
        float4 v = *p;
        v.x = fmaf(v.x, sc, sh);
        v.y = fmaf(v.y, sc, sh);
        v.z = fmaf(v.z, sc, sh);
        v.w = fmaf(v.w, sc, sh);
        *p = v;
    } else if (base < N) {
        for (int t = base; t < N; ++t) y[(long)d * N + t] = fmaf(y[(long)d * N + t], sc, sh);
    }
}

// ---------------- launcher ----------------
extern "C" void kernel_launch(void* const* d_in, const int* in_sizes, int n_in,
                              void* d_out, int out_size, void* d_ws, size_t ws_size,
                              hipStream_t stream) {
    const float* data_in = (const float*)d_in[0];
    const int*   neigh   = (const int*)d_in[1];
    const float* weight  = (const float*)d_in[2];
    const float* gamma   = (const float*)d_in[3];
    const float* beta    = (const float*)d_in[4];
    float* out = (float*)d_out;

    const int N = in_sizes[1] / KK;

    float* xT = (float*)d_ws;                        // N*32 floats
    const int nblk  = (N + TPB - 1) / TPB;           // conv blocks
    const int nrows = nblk * (TPB / 64);             // waves (partial rows)
    float* partial = xT + (size_t)N * CIN;           // nrows*64 floats
    float* ss      = partial + (size_t)nrows * 64;   // 64 floats

    transpose_k<<<(N + 31) / 32, 256, 0, stream>>>(data_in, xT, N);
    conv_k<<<nblk, TPB, 0, stream>>>(xT, neigh, weight, out, partial, N);
    stats_k<<<1, 256, 0, stream>>>(partial, nrows, gamma, beta, ss, N);
    dim3 ngrid(((N + 3) / 4 + 255) / 256, COUT);
    norm_k<<<ngrid, 256, 0, stream>>>(out, ss, N);
}

// Round 3
// 235.765 us; speedup vs baseline: 25.4813x; 1.4449x over previous
//
#include <hip/hip_runtime.h>

#define CIN  32
#define COUT 32
#define KK   27
#define TPB  64   // conv block = 1 wave: 1563 blocks, even CU distribution

// ---------------- Kernel 1: transpose x [Cin,N] -> xT [N,Cin] ----------------
__global__ __launch_bounds__(256) void transpose_k(const float* __restrict__ in,
                                                   float* __restrict__ xT, int N) {
    __shared__ float tile[32][33];
    int n0 = blockIdx.x * 32;
    int tx = threadIdx.x & 31;
    int ty = threadIdx.x >> 5;  // 0..7
#pragma unroll
    for (int c = ty; c < 32; c += 8) {
        int n = n0 + tx;
        tile[c][tx] = (n < N) ? in[(long)c * N + n] : 0.f;
    }
    __syncthreads();
#pragma unroll
    for (int nn = ty; nn < 32; nn += 8) {
        int n = n0 + nn;
        if (n < N) xT[(long)n * 32 + tx] = tile[tx][nn];
    }
}

// ---------------- Kernel 2: conv + per-wave BN partials ----------------
// 1 node/thread, 1 wave/block. acc[32] in VGPRs; weights wave-uniform ->
// SGPR s_loads. Gather pipelined one tap ahead in named float4 regs, with
// sched_barrier fences so the loads issue as a batch before the FMA block.
__global__ __launch_bounds__(TPB, 4) void conv_k(const float* __restrict__ xT,
                                                 const int* __restrict__ neigh,
                                                 const float* __restrict__ weight,
                                                 float* __restrict__ y,        // d_out, [COUT][N]
                                                 float* __restrict__ partial,  // [64][nrows]
                                                 int N, int nrows) {
    const int tid   = threadIdx.x;
    const int n     = blockIdx.x * TPB + tid;
    const bool valid = (n < N);
    const long nb   = (long)(valid ? n : 0) * KK;

    float acc[COUT];
#pragma unroll
    for (int d = 0; d < COUT; ++d) acc[d] = 0.f;

    int m  = neigh[nb];
    int m2 = neigh[nb + 1];

    // prologue: load tap 0's row
    const float4* xr = (const float4*)(xT + (long)m * CIN);
    float4 x0 = xr[0], x1 = xr[1], x2 = xr[2], x3 = xr[3];
    float4 x4 = xr[4], x5 = xr[5], x6 = xr[6], x7 = xr[7];

#define DOT4(xq, cb) do {                                      \
        const float* W0 = wk + (cb + 0) * COUT;                \
        const float* W1 = wk + (cb + 1) * COUT;                \
        const float* W2 = wk + (cb + 2) * COUT;                \
        const float* W3 = wk + (cb + 3) * COUT;                \
        _Pragma("unroll")                                      \
        for (int d = 0; d < COUT; ++d) {                       \
            float t = acc[d];                                  \
            t = fmaf((xq).x, W0[d], t);                        \
            t = fmaf((xq).y, W1[d], t);                        \
            t = fmaf((xq).z, W2[d], t);                        \
            t = fmaf((xq).w, W3[d], t);                        \
            acc[d] = t;                                        \
        }                                                      \
    } while (0)

#pragma unroll 1
    for (int k = 0; k < KK; ++k) {
        // batched prefetch of next tap's row (independent of FMAs below)
        const float4* xp = (const float4*)(xT + (long)m2 * CIN);
        float4 p0 = xp[0], p1 = xp[1], p2 = xp[2], p3 = xp[3];
        float4 p4 = xp[4], p5 = xp[5], p6 = xp[6], p7 = xp[7];
        m2 = neigh[nb + ((k + 2 < KK) ? (k + 2) : (KK - 1))];

        __builtin_amdgcn_sched_barrier(0);  // loads stay above, FMAs below

        const float* wk = weight + k * (CIN * COUT);
        DOT4(x0, 0);  DOT4(x1, 4);  DOT4(x2, 8);  DOT4(x3, 12);
        DOT4(x4, 16); DOT4(x5, 20); DOT4(x6, 24); DOT4(x7, 28);

        __builtin_amdgcn_sched_barrier(0);  // rotation (and its waitcnt) stays after FMAs

        x0 = p0; x1 = p1; x2 = p2; x3 = p3;
        x4 = p4; x5 = p5; x6 = p6; x7 = p7;
    }
#undef DOT4

    // write y in [d][N] layout (coalesced per d)
    if (valid) {
#pragma unroll
        for (int d = 0; d < COUT; ++d) y[(long)d * N + n] = acc[d];
    } else {
#pragma unroll
        for (int d = 0; d < COUT; ++d) acc[d] = 0.f;
    }

    // per-wave butterfly reduction -> partial[d][block], transposed so the
    // column-reduce kernel reads coalesced
    const int lane = tid & 63;
    const int wrow = blockIdx.x;
#pragma unroll
    for (int d = 0; d < COUT; ++d) {
        float s = acc[d];
        float q = acc[d] * acc[d];
#pragma unroll
        for (int off = 1; off < 64; off <<= 1) {
            s += __shfl_xor(s, off, 64);
            q += __shfl_xor(q, off, 64);
        }
        if (lane == 0) {
            partial[(long)d * nrows + wrow]        = s;
            partial[(long)(d + 32) * nrows + wrow] = q;
        }
    }
}

// ---------------- Kernel 3a: column reduce partial[64][nrows] -> tot[64] ----
__global__ __launch_bounds__(256) void stats1_k(const float* __restrict__ partial,
                                                int nrows, float* __restrict__ tot) {
    __shared__ float red[256];
    const int col = blockIdx.x;  // 0..63
    const float* row = partial + (long)col * nrows;
    float s = 0.f;
    for (int r = threadIdx.x; r < nrows; r += 256) s += row[r];
    red[threadIdx.x] = s;
    __syncthreads();
    for (int w = 128; w >= 64; w >>= 1) {
        if (threadIdx.x < w) red[threadIdx.x] += red[threadIdx.x + w];
        __syncthreads();
    }
    if (threadIdx.x < 64) {
        float v = red[threadIdx.x];
#pragma unroll
        for (int off = 1; off < 64; off <<= 1) v += __shfl_xor(v, off, 64);
        if (threadIdx.x == 0) tot[col] = v;
    }
}

// ---------------- Kernel 3b: finalize scale/shift ----------------
__global__ __launch_bounds__(64) void stats2_k(const float* __restrict__ tot,
                                               const float* __restrict__ gamma,
                                               const float* __restrict__ beta,
                                               float* __restrict__ ss, int N) {
    int d = threadIdx.x;
    if (d < 32) {
        float mean = tot[d] / (float)N;
        float var  = tot[d + 32] / (float)N - mean * mean;
        float sc   = gamma[d] * rsqrtf(var + 1e-3f);
        ss[d]      = sc;
        ss[d + 32] = beta[d] - mean * sc;
    }
}

// ---------------- Kernel 4: in-place normalize of y ----------------
__global__ __launch_bounds__(256) void norm_k(float* __restrict__ y,
                                              const float* __restrict__ ss, int N) {
    int d = blockIdx.y;
    int i = blockIdx.x * blockDim.x + threadIdx.x;
    float sc = ss[d];
    float sh = ss[d + 32];
    int base = i * 4;
    if (base + 3 < N) {
        float4* p = (float4*)(y + (long)d * N + base);
        float4 v = *p;
        v.x = fmaf(v.x, sc, sh);
        v.y = fmaf(v.y, sc, sh);
        v.z = fmaf(v.z, sc, sh);
        v.w = fmaf(v.w, sc, sh);
        *p = v;
    } else if (base < N) {
        for (int t = base; t < N; ++t) y[(long)d * N + t] = fmaf(y[(long)d * N + t], sc, sh);
    }
}

// ---------------- launcher ----------------
extern "C" void kernel_launch(void* const* d_in, const int* in_sizes, int n_in,
                              void* d_out, int out_size, void* d_ws, size_t ws_size,
                              hipStream_t stream) {
    const float* data_in = (const float*)d_in[0];
    const int*   neigh   = (const int*)d_in[1];
    const float* weight  = (const float*)d_in[2];
    const float* gamma   = (const float*)d_in[3];
    const float* beta    = (const float*)d_in[4];
    float* out = (float*)d_out;

    const int N = in_sizes[1] / KK;

    float* xT = (float*)d_ws;                        // N*32 floats
    const int nblk  = (N + TPB - 1) / TPB;           // conv blocks
    const int nrows = nblk;                          // 1 wave per block
    float* partial = xT + (size_t)N * CIN;           // 64*nrows floats
    float* tot     = partial + (size_t)64 * nrows;   // 64 floats
    float* ss      = tot + 64;                       // 64 floats

    transpose_k<<<(N + 31) / 32, 256, 0, stream>>>(data_in, xT, N);
    conv_k<<<nblk, TPB, 0, stream>>>(xT, neigh, weight, out, partial, N, nrows);
    stats1_k<<<64, 256, 0, stream>>>(partial, nrows, tot);
    stats2_k<<<1, 64, 0, stream>>>(tot, gamma, beta, ss, N);
    dim3 ngrid(((N + 3) / 4 + 255) / 256, COUT);
    norm_k<<<ngrid, 256, 0, stream>>>(out, ss, N);
}